// Round 16
// baseline (278.466 us; speedup 1.0000x reference)
//
#include <hip/hip_runtime.h>
#include <math.h>

#define S_LEN  4096
#define BATCH  4
#define DMODEL 1024
#define NHEADS 16
#define DHEAD  64
#define WIN    128

typedef _Float16 half8   __attribute__((ext_vector_type(8)));
typedef _Float16 half4_t __attribute__((ext_vector_type(4)));
typedef float    floatx4 __attribute__((ext_vector_type(4)));

__device__ __forceinline__ void gload16(const void* g, void* l) {
    __builtin_amdgcn_global_load_lds(
        (const __attribute__((address_space(1))) void*)g,
        (__attribute__((address_space(3))) void*)l, 16, 0, 0);
}

// ---------------- fp32 -> fp16 conversion, one launch for x + 4 weights ---
__global__ __launch_bounds__(256)
void cvt5_f32_f16(const float4* __restrict__ x,  half4_t* __restrict__ xo, int n4x,
                  const float4* __restrict__ w0, const float4* __restrict__ w1,
                  const float4* __restrict__ w2, const float4* __restrict__ w3,
                  half4_t* __restrict__ o0, half4_t* __restrict__ o1,
                  half4_t* __restrict__ o2, half4_t* __restrict__ o3, int n4w) {
    const int y = blockIdx.y;
    const float4* in  = y == 0 ? x  : (y == 1 ? w0 : (y == 2 ? w1 : (y == 3 ? w2 : w3)));
    half4_t*      out = y == 0 ? xo : (y == 1 ? o0 : (y == 2 ? o1 : (y == 3 ? o2 : o3)));
    const int n4 = y == 0 ? n4x : n4w;
    for (int i = blockIdx.x * blockDim.x + threadIdx.x; i < n4;
         i += gridDim.x * blockDim.x) {
        const float4 a = in[i];
        half4_t h;
        h[0] = (_Float16)a.x; h[1] = (_Float16)a.y;
        h[2] = (_Float16)a.z; h[3] = (_Float16)a.w;
        out[i] = h;
    }
}

// ---------------- f16 MFMA GEMM, 128x128 tile, BK=64, 2 blocks/CU ---------
// 512 threads, 8 waves (4M x 2N), per-wave 32x64 out (acc[2][4]=32 VGPR).
// LDS 64 KiB (2-dbuf x 16KB A + 16KB B) + <=128 VGPR (__launch_bounds__
// (512,4)) -> 2 blocks/CU = 16 waves/CU = 4 waves/SIMD: the barrier/vmcnt
// stall of one block hides under the other's MFMA (m114) — the missing
// occupancy in every prior variant (all were 8 waves/CU, MfmaUtil ~37).
// Schedule = r14's correctness-proven 2-barrier loop:
//   RD all frags (12 b128); lgkm(0); barrier;     // WAR: readers drained
//   stage(t+2) (4 gload16, parity-t buffers);
//   16 MFMA; vmcnt(4)/(0); barrier;               // RAW: t+1 landed, all-wave
// K-ascending, kc 0,1 accumulation order == r9 -> bit-identical absmax.
// LDS XOR swizzle slot^=(row&7); linear gload_lds dest + pre-swizzled src.
// MODE 0: f16 out; slab z=n0>>10: z=0,1 -> [B,H,S,Dh]; z=2 -> V^T [B,H,Dh,S].
// MODE 1: fp32 flat [M,1024], bias B0.
template<int MODE, int NTN>
__global__ __launch_bounds__(512, 4)
void gemm_occ(const _Float16* __restrict__ A, const _Float16* __restrict__ W,
              const float* __restrict__ B0, const float* __restrict__ B1,
              const float* __restrict__ B2, void* __restrict__ out_base)
{
    constexpr int K  = DMODEL;
    constexpr int nt = K / 64;                   // 16 K-tiles
    const int bid  = blockIdx.x;
    const int nwg8 = (128 * NTN) >> 3;           // grid = 128*NTN, %8 == 0
    const int swz  = (bid & 7) * nwg8 + (bid >> 3);
    const int i0   = (swz / NTN) * 128;
    const int n0   = (swz % NTN) * 128;

    __shared__ _Float16 As[2][128 * 64];         // 2 x 16 KiB
    __shared__ _Float16 Bs[2][128 * 64];         // 2 x 16 KiB  (total 64 KiB)

    const int tid  = threadIdx.x;
    const int lane = tid & 63;
    const int wid  = tid >> 6;                   // 0..7
    const int wr   = wid >> 1;                   // 0..3 (M quarter)
    const int wc   = wid & 1;                    // 0..1 (N half)
    const int fr   = lane & 15;
    const int fh   = lane >> 4;
    const int sw8  = fr & 7;
    const int ok0  = ((fh) ^ sw8) * 8;           // kc=0 slot (f16 units)
    const int ok1  = ((4 + fh) ^ sw8) * 8;       // kc=1 slot
    const int arow = (wr * 32 + fr) * 64;        // + mi*16*64
    const int brow = (wc * 64 + fr) * 64;        // + ni*16*64

    const int srow = tid >> 3;                   // 0..63 (+64 for 2nd load)
    const int ssw  = ((tid & 7) ^ (srow & 7)) << 3;
    const _Float16* baseA = A + (size_t)(i0 + srow) * K + ssw;
    const _Float16* baseB = W + (size_t)(n0 + srow) * K + ssw;
    const int ldso = tid * 8;

    floatx4 acc[2][4];
    #pragma unroll
    for (int mi = 0; mi < 2; ++mi)
        #pragma unroll
        for (int ni = 0; ni < 4; ++ni) acc[mi][ni] = (floatx4)0.f;

    half8 a[2][2], b[4][2];

#define ST_AB(TT)                                                            \
    do {                                                                     \
        _Float16* dA = &As[(TT) & 1][ldso];                                  \
        _Float16* dB = &Bs[(TT) & 1][ldso];                                  \
        const _Float16* sA = baseA + (TT) * 64;                              \
        const _Float16* sB = baseB + (TT) * 64;                              \
        gload16(sA, dA);                                                     \
        gload16(sA + (size_t)64 * K, dA + 4096);                             \
        gload16(sB, dB);                                                     \
        gload16(sB + (size_t)64 * K, dB + 4096);                             \
    } while (0)

    // prologue: stage t0 (4 loads) + t1 (4 loads); force t0's 4; barrier
    ST_AB(0);
    ST_AB(1);
    asm volatile("s_waitcnt vmcnt(4)" ::: "memory");
    __builtin_amdgcn_sched_barrier(0);
    __builtin_amdgcn_s_barrier();

    for (int t = 0; t < nt; ++t) {
        const int d = t & 1;
        const bool st = (t + 2) < nt;

        // ---- RD: wave reads its own A-quarter / B-half (12 b128) ----
        #pragma unroll
        for (int mi = 0; mi < 2; ++mi) {
            a[mi][0] = *(const half8*)&As[d][arow + mi * 1024 + ok0];
            a[mi][1] = *(const half8*)&As[d][arow + mi * 1024 + ok1];
        }
        #pragma unroll
        for (int ni = 0; ni < 4; ++ni) {
            b[ni][0] = *(const half8*)&Bs[d][brow + ni * 1024 + ok0];
            b[ni][1] = *(const half8*)&Bs[d][brow + ni * 1024 + ok1];
        }
        asm volatile("s_waitcnt lgkmcnt(0)" ::: "memory");
        __builtin_amdgcn_sched_barrier(0);
        __builtin_amdgcn_s_barrier();   // all waves' reads drained -> WAR-safe

        // ---- stage tile t+2 into parity-t buffers (4 gload16) ----
        if (st) ST_AB(t + 2);

        // ---- 16 MFMA (kc 0,1 ascending == r9 order) ----
        __builtin_amdgcn_s_setprio(1);
        #pragma unroll
        for (int kc = 0; kc < 2; ++kc)
            #pragma unroll
            for (int mi = 0; mi < 2; ++mi)
                #pragma unroll
                for (int ni = 0; ni < 4; ++ni)
                    acc[mi][ni] = __builtin_amdgcn_mfma_f32_16x16x32_f16(
                        a[mi][kc], b[ni][kc], acc[mi][ni], 0, 0, 0);
        __builtin_amdgcn_s_setprio(0);

        // ---- force tile t+1 landed (every wave) before next RD ----
        if (st) {
            asm volatile("s_waitcnt vmcnt(4)" ::: "memory");
        } else if (t + 1 < nt) {
            asm volatile("s_waitcnt vmcnt(0)" ::: "memory");
        }
        __builtin_amdgcn_sched_barrier(0);
        __builtin_amdgcn_s_barrier();
    }
#undef ST_AB

    // ---- epilogue: C/D layout col=lane&15, row=(lane>>4)*4+reg ----
    const int r0 = (lane >> 4) * 4;
    const int z  = (MODE == 0) ? (n0 >> 10) : 0;
    const float* bz = (MODE == 1) ? B0 : (z == 0 ? B0 : (z == 1 ? B1 : B2));

    #pragma unroll
    for (int ni = 0; ni < 4; ++ni) {
        const int gc   = n0 + wc * 64 + ni * 16 + fr;
        const int gcol = gc & (DMODEL - 1);
        const float bv = bz[gcol];
        #pragma unroll
        for (int mi = 0; mi < 2; ++mi) {
            const int gr = i0 + wr * 32 + mi * 16 + r0;
            const floatx4 v = acc[mi][ni];
            if (MODE == 0) {
                _Float16* outh = (_Float16*)out_base
                               + (size_t)z * ((size_t)16384 * DMODEL);
                const int bb = gr >> 12;
                const int sp = gr & (S_LEN - 1);
                const int hh = gcol >> 6;
                const int dh = gcol & 63;
                if (z < 2) {
                    #pragma unroll
                    for (int r = 0; r < 4; ++r)
                        outh[((((size_t)(bb * NHEADS + hh)) * S_LEN + sp + r) << 6) + dh] =
                            (_Float16)(v[r] + bv);
                } else {
                    half4_t hv;
                    hv[0] = (_Float16)(v[0] + bv); hv[1] = (_Float16)(v[1] + bv);
                    hv[2] = (_Float16)(v[2] + bv); hv[3] = (_Float16)(v[3] + bv);
                    *(half4_t*)&outh[(((size_t)(bb * NHEADS + hh)) * DHEAD + dh) * S_LEN + sp] = hv;
                }
            } else {
                float* out = (float*)out_base;
                #pragma unroll
                for (int r = 0; r < 4; ++r)
                    out[(size_t)(gr + r) * DMODEL + gcol] = v[r] + bv;
            }
        }
    }
}

// ---------------- MFMA windowed attention, wave-local exact prefix scan ---
// (byte-identical to r13 verified kernel)
__global__ __launch_bounds__(256)
void attn_mfma(const _Float16* __restrict__ qh_, const _Float16* __restrict__ kh_,
               const _Float16* __restrict__ vth_, _Float16* __restrict__ o)
{
    __shared__ __align__(16) _Float16 Qs[64 * 64];
    __shared__ __align__(16) _Float16 Ks[64 * 64];
    __shared__ __align__(16) _Float16 Vt[64 * 64];
    __shared__ __align__(16) float    SP[64 * 68];
    __shared__ __align__(16) _Float16 P16[64 * 64];
    __shared__ float TqL[64];

    const int tid   = threadIdx.x;
    const int lane  = tid & 63;
    const int w     = tid >> 6;
    const int qbase = blockIdx.x * 64;
    const int head  = blockIdx.y, b = blockIdx.z;
    const size_t bh = (size_t)(b * NHEADS + head);

    const _Float16* qg = qh_  + bh * (size_t)(S_LEN * DHEAD);
    const _Float16* kg = kh_  + bh * (size_t)(S_LEN * DHEAD);
    const _Float16* vg = vth_ + bh * (size_t)(DHEAD * S_LEN);

    const int fr  = lane & 15;
    const int fh  = lane >> 4;
    const int sqt = 16 * w + (lane >> 2);
    const int sg  = lane & 3;
    const int gb  = lane & ~3;

    #pragma unroll
    for (int rep = 0; rep < 2; ++rep) {
        const int c = tid + 256 * rep;
        const int row = c >> 3, sll = c & 7;
        gload16(qg + (size_t)(qbase + row) * 64 + (size_t)((sll ^ (row & 7)) * 8),
                Qs + (size_t)c * 8);
    }

    float mq = -INFINITY;
    float tq = 0.f;

    floatx4 Oacc[4];
    #pragma unroll
    for (int ni = 0; ni < 4; ++ni) Oacc[ni] = (floatx4)0.f;

    for (int c = 0; c < 5; ++c) {
        const int jlo = qbase - WIN + c * 64;
        if (jlo < 0 || jlo >= S_LEN) continue;
        const int base_rel = jlo - qbase + WIN;

        __syncthreads();

        #pragma unroll
        for (int rep = 0; rep < 2; ++rep) {
            const int cc = tid + 256 * rep;
            const int row = cc >> 3, sll = cc & 7;
            gload16(kg + (size_t)(jlo + row) * 64 + (size_t)((sll ^ (row & 7)) * 8),
                    Ks + (size_t)cc * 8);
            gload16(vg + (size_t)row * S_LEN + jlo + (size_t)((sll ^ (row & 7)) * 8),
                    Vt + (size_t)cc * 8);
        }
        __syncthreads();

        {
            floatx4 acc[4];
            #pragma unroll
            for (int ni = 0; ni < 4; ++ni) acc[ni] = (floatx4)0.f;
            half8 a[2];
            #pragma unroll
            for (int kc = 0; kc < 2; ++kc) {
                const int row = 16 * w + fr;
                a[kc] = *(const half8*)&Qs[row * 64 + ((fh + 4 * kc) ^ (row & 7)) * 8];
            }
            #pragma unroll
            for (int ni = 0; ni < 4; ++ni)
                #pragma unroll
                for (int kc = 0; kc < 2; ++kc) {
                    const int tr = 16 * ni + fr;
                    half8 bf = *(const half8*)&Ks[tr * 64 + ((fh + 4 * kc) ^ (tr & 7)) * 8];
                    acc[ni] = __builtin_amdgcn_mfma_f32_16x16x32_f16(a[kc], bf, acc[ni], 0, 0, 0);
                }
            #pragma unroll
            for (int ni = 0; ni < 4; ++ni)
                #pragma unroll
                for (int r = 0; r < 4; ++r)
                    SP[(16 * w + 4 * fh + r) * 68 + fr + 16 * ni] = acc[ni][r] * 0.125f;
        }
        asm volatile("s_waitcnt lgkmcnt(0)" ::: "memory");
        __builtin_amdgcn_sched_barrier(0);

        {
            float sv[16], run[16];
            float m_run = -INFINITY;
            #pragma unroll
            for (int u = 0; u < 4; ++u) {
                const float4 s4 = *(const float4*)&SP[sqt * 68 + sg * 16 + 4 * u];
                const float se[4] = {s4.x, s4.y, s4.z, s4.w};
                #pragma unroll
                for (int e = 0; e < 4; ++e) {
                    const int i = 4 * u + e;
                    const int rel = base_rel + sg * 16 + i - sqt;
                    const bool valid = (rel >= 0) && (rel <= 2 * WIN);
                    const float s = valid ? se[e] : -INFINITY;
                    sv[i] = s;
                    m_run = fmaxf(m_run, s);
                    run[i] = m_run;
                }
            }
            const float cm = m_run;
            const float c0 = __shfl(cm, gb + 0);
            const float c1 = __shfl(cm, gb + 1);
            const float c2 = __shfl(cm, gb + 2);
            const float c3 = __shfl(cm, gb + 3);
            float pre = mq;
            if (sg > 0) pre = fmaxf(pre, c0);
            if (sg > 1) pre = fmaxf(pre, c1);
            if (sg > 2) pre = fmaxf(pre, c2);

            float tl = 0.f;
            _Float16 pf[16];
            #pragma unroll
            for (int i = 0; i < 16; ++i) {
                const float wm = fmaxf(pre, run[i]);
                const float p = (sv[i] != -INFINITY) ? __expf(sv[i] - wm) : 0.f;
                tl += p;
                pf[i] = (_Float16)p;
            }
            #pragma unroll
            for (int u = 0; u < 2; ++u) {
                half8 h8;
                #pragma unroll
                for (int e = 0; e < 8; ++e) h8[e] = pf[8 * u + e];
                *(half8*)&P16[sqt * 64 + ((2 * sg + u) ^ (sqt & 7)) * 8] = h8;
            }
            const float t0 = __shfl(tl, gb + 0);
            const float t1 = __shfl(tl, gb + 1);
            const float t2 = __shfl(tl, gb + 2);
            const float t3 = __shfl(tl, gb + 3);
            tq += t0 + t1 + t2 + t3;
            mq = fmaxf(mq, fmaxf(fmaxf(c0, c1), fmaxf(c2, c3)));
        }
        asm volatile("s_waitcnt lgkmcnt(0)" ::: "memory");
        __builtin_amdgcn_sched_barrier(0);

        {
            half8 pa[2];
            #pragma unroll
            for (int kc = 0; kc < 2; ++kc) {
                const int row = 16 * w + fr;
                pa[kc] = *(const half8*)&P16[row * 64 + ((fh + 4 * kc) ^ (row & 7)) * 8];
            }
            #pragma unroll
            for (int ni = 0; ni < 4; ++ni)
                #pragma unroll
                for (int kc = 0; kc < 2; ++kc) {
                    const int dr = 16 * ni + fr;
                    half8 bf = *(const half8*)&Vt[dr * 64 + ((fh + 4 * kc) ^ (dr & 7)) * 8];
                    Oacc[ni] = __builtin_amdgcn_mfma_f32_16x16x32_f16(pa[kc], bf, Oacc[ni], 0, 0, 0);
                }
        }
    }

    if (sg == 0) TqL[sqt] = tq;
    asm volatile("s_waitcnt lgkmcnt(0)" ::: "memory");
    __builtin_amdgcn_sched_barrier(0);

    #pragma unroll
    for (int ni = 0; ni < 4; ++ni)
        #pragma unroll
        for (int r = 0; r < 4; ++r) {
            const int q  = 16 * w + 4 * fh + r;
            const float inv = 1.0f / TqL[q];
            o[((size_t)(b * S_LEN + qbase + q) * NHEADS + head) * DHEAD + fr + 16 * ni] =
                (_Float16)(Oacc[ni][r] * inv);
        }
}

extern "C" void kernel_launch(void* const* d_in, const int* in_sizes, int n_in,
                              void* d_out, int out_size, void* d_ws, size_t ws_size,
                              hipStream_t stream) {
    const float* x  = (const float*)d_in[0];
    const float* wq = (const float*)d_in[1];
    const float* bq = (const float*)d_in[2];
    const float* wk = (const float*)d_in[3];
    const float* bk = (const float*)d_in[4];
    const float* wv = (const float*)d_in[5];
    const float* bv = (const float*)d_in[6];
    const float* wo = (const float*)d_in[7];
    const float* bo = (const float*)d_in[8];

    const size_t BUF = (size_t)BATCH * S_LEN * DMODEL;   // 16,777,216 elems
    _Float16* xh  = (_Float16*)d_ws;
    _Float16* qh  = xh + BUF;
    _Float16* kh  = qh + BUF;       // qh/kh/vth consecutive (z-slab offset)
    _Float16* vth = kh + BUF;
    _Float16* oh  = vth + BUF;
    _Float16* wqh = oh + BUF;       // wqh/wkh/wvh consecutive = W_all [3072,1024]
    _Float16* wkh = wqh + DMODEL * DMODEL;
    _Float16* wvh = wkh + DMODEL * DMODEL;
    _Float16* woh = wvh + DMODEL * DMODEL;

    // 1) fp32 -> f16 conversions (single launch; y=0 x, y=1..4 weights)
    cvt5_f32_f16<<<dim3(512, 5), 256, 0, stream>>>(
        (const float4*)x, (half4_t*)xh, (int)(BUF / 4),
        (const float4*)wq, (const float4*)wk, (const float4*)wv, (const float4*)wo,
        (half4_t*)wqh, (half4_t*)wkh, (half4_t*)wvh, (half4_t*)woh,
        DMODEL * DMODEL / 4);

    // 2) fused QKV projection: [16384,1024] @ [3072,1024]^T (2 blocks/CU)
    gemm_occ<0, 24><<<128 * 24, 512, 0, stream>>>(xh, wqh, bq, bk, bv, (void*)qh);

    // 3) MFMA windowed attention -> oh f16 [B,S,H,Dh]
    dim3 gattn(S_LEN / 64, NHEADS, BATCH);
    attn_mfma<<<gattn, 256, 0, stream>>>(qh, kh, vth, oh);

    // 4) output projection -> fp32 d_out (2 blocks/CU)
    gemm_occ<1, 8><<<128 * 8, 512, 0, stream>>>(oh, woh, bo, bo, bo, d_out);
}

// Round 17
// 247.581 us; speedup vs baseline: 1.1247x; 1.1247x over previous
//
#include <hip/hip_runtime.h>
#include <math.h>

#define S_LEN  4096
#define BATCH  4
#define DMODEL 1024
#define NHEADS 16
#define DHEAD  64
#define WIN    128

typedef _Float16 half8   __attribute__((ext_vector_type(8)));
typedef _Float16 half4_t __attribute__((ext_vector_type(4)));
typedef float    floatx4 __attribute__((ext_vector_type(4)));

__device__ __forceinline__ void gload16(const void* g, void* l) {
    __builtin_amdgcn_global_load_lds(
        (const __attribute__((address_space(1))) void*)g,
        (__attribute__((address_space(3))) void*)l, 16, 0, 0);
}

// ---------------- fp32 -> fp16 conversion, one launch for x + 4 weights ---
__global__ __launch_bounds__(256)
void cvt5_f32_f16(const float4* __restrict__ x,  half4_t* __restrict__ xo, int n4x,
                  const float4* __restrict__ w0, const float4* __restrict__ w1,
                  const float4* __restrict__ w2, const float4* __restrict__ w3,
                  half4_t* __restrict__ o0, half4_t* __restrict__ o1,
                  half4_t* __restrict__ o2, half4_t* __restrict__ o3, int n4w) {
    const int y = blockIdx.y;
    const float4* in  = y == 0 ? x  : (y == 1 ? w0 : (y == 2 ? w1 : (y == 3 ? w2 : w3)));
    half4_t*      out = y == 0 ? xo : (y == 1 ? o0 : (y == 2 ? o1 : (y == 3 ? o2 : o3)));
    const int n4 = y == 0 ? n4x : n4w;
    for (int i = blockIdx.x * blockDim.x + threadIdx.x; i < n4;
         i += gridDim.x * blockDim.x) {
        const float4 a = in[i];
        half4_t h;
        h[0] = (_Float16)a.x; h[1] = (_Float16)a.y;
        h[2] = (_Float16)a.z; h[3] = (_Float16)a.w;
        out[i] = h;
    }
}

// ---------------- f16 MFMA GEMM, 256x256 tile, BK=64, 4-phase/K-tile ------
// r9 champion schedule (verified 254/250.8us) — byte-identical to r12/r13.
template<int MODE, int NTN>
__global__ __launch_bounds__(512)
void gemm8p(const _Float16* __restrict__ A, const _Float16* __restrict__ W,
            const float* __restrict__ B0, const float* __restrict__ B1,
            const float* __restrict__ B2, void* __restrict__ out_base)
{
    constexpr int K  = DMODEL;
    constexpr int nt = K / 64;                   // 16 K-tiles
    const int bid  = blockIdx.x;
    const int nwg8 = (64 * NTN) >> 3;
    const int swz  = (bid & 7) * nwg8 + (bid >> 3);
    const int i0   = (swz / NTN) * 256;
    const int n0   = (swz % NTN) * 256;

    __shared__ _Float16 As[4][128 * 64];         // [parity*2 + half]
    __shared__ _Float16 Bs[4][128 * 64];

    const int tid  = threadIdx.x;
    const int lane = tid & 63;
    const int wid  = tid >> 6;
    const int wr   = wid >> 2;
    const int wc   = wid & 3;
    const int fr   = lane & 15;
    const int fh   = lane >> 4;
    const int sw8  = fr & 7;
    const int ok0  = ((fh) ^ sw8) * 8;
    const int ok1  = ((4 + fh) ^ sw8) * 8;
    const int arow = (wr * 16 + fr) * 64;
    const int brow = (wc * 16 + fr) * 64;

    const int srow = tid >> 3;
    const int ssw  = ((tid & 7) ^ (srow & 7)) << 3;
    const _Float16* baseA = A + (size_t)(i0 + srow) * K + ssw;
    const _Float16* baseB = W + (size_t)(n0 + srow) * K + ssw;
    const int ldso = tid * 8;

    floatx4 acc[8][4];
    #pragma unroll
    for (int mi = 0; mi < 8; ++mi)
        #pragma unroll
        for (int ni = 0; ni < 4; ++ni) acc[mi][ni] = (floatx4)0.f;

    half8 a_lo[4][2], a_hi[4][2], b_lo[2][2], b_hi[2][2];

#define ST_A(TT, H)                                                          \
    do {                                                                     \
        _Float16* d_ = &As[(((TT) & 1) << 1) | (H)][ldso];                   \
        const _Float16* s_ = baseA + (size_t)((H) * 128) * K + (TT) * 64;    \
        gload16(s_, d_);                                                     \
        gload16(s_ + (size_t)64 * K, d_ + 4096);                             \
    } while (0)
#define ST_B(TT, H)                                                          \
    do {                                                                     \
        _Float16* d_ = &Bs[(((TT) & 1) << 1) | (H)][ldso];                   \
        const _Float16* s_ = baseB + (size_t)((H) * 128) * K + (TT) * 64;    \
        gload16(s_, d_);                                                     \
        gload16(s_ + (size_t)64 * K, d_ + 4096);                             \
    } while (0)
#define RD_A(DST, DB, H)                                                     \
    _Pragma("unroll")                                                        \
    for (int mi = 0; mi < 4; ++mi) {                                         \
        DST[mi][0] = *(const half8*)&As[(DB) | (H)][arow + mi * 2048 + ok0]; \
        DST[mi][1] = *(const half8*)&As[(DB) | (H)][arow + mi * 2048 + ok1]; \
    }
#define RD_B(DST, DB, H)                                                     \
    _Pragma("unroll")                                                        \
    for (int ni = 0; ni < 2; ++ni) {                                         \
        DST[ni][0] = *(const half8*)&Bs[(DB) | (H)][brow + ni * 4096 + ok0]; \
        DST[ni][1] = *(const half8*)&Bs[(DB) | (H)][brow + ni * 4096 + ok1]; \
    }
#define MFMA16(MB, NB, AA, BB)                                               \
    __builtin_amdgcn_s_setprio(1);                                           \
    _Pragma("unroll")                                                        \
    for (int kc = 0; kc < 2; ++kc)                                           \
        _Pragma("unroll")                                                    \
        for (int mi = 0; mi < 4; ++mi)                                       \
            _Pragma("unroll")                                                \
            for (int ni = 0; ni < 2; ++ni)                                   \
                acc[MB + mi][NB + ni] = __builtin_amdgcn_mfma_f32_16x16x32_f16( \
                    AA[mi][kc], BB[ni][kc], acc[MB + mi][NB + ni], 0, 0, 0); \
    __builtin_amdgcn_s_setprio(0);
#define PHEND                                                                \
    asm volatile("s_waitcnt lgkmcnt(0)" ::: "memory");                       \
    __builtin_amdgcn_sched_barrier(0);                                       \
    __builtin_amdgcn_s_barrier();

    // ---- prologue: stage t0 + t1 fully; force t0; first lo-frag reads ----
    ST_A(0, 0); ST_B(0, 0); ST_B(0, 1); ST_A(0, 1);
    ST_A(1, 0); ST_B(1, 1); ST_A(1, 1); ST_B(1, 0);
    asm volatile("s_waitcnt vmcnt(8)" ::: "memory");
    __builtin_amdgcn_sched_barrier(0);
    __builtin_amdgcn_s_barrier();
    RD_A(a_lo, 0, 0); RD_B(b_lo, 0, 0);
    asm volatile("s_waitcnt lgkmcnt(0)" ::: "memory");
    __builtin_amdgcn_sched_barrier(0);

    for (int t = 0; t < nt; ++t) {
        const int d2 = (t & 1) << 1;
        const bool st = (t + 2) < nt;
        // ---- P1: q(0,0); reads B1; NO stage (WAR-safe window for A[d2|0]) --
        RD_B(b_hi, d2, 1);
        MFMA16(0, 0, a_lo, b_lo);
        PHEND;
        // ---- P2: q(0,1); reads A1; stage B1(t+2) + A0(t+2) ----
        RD_A(a_hi, d2, 1);
        if (st) { ST_B(t + 2, 1); ST_A(t + 2, 0); }
        MFMA16(0, 2, a_lo, b_hi);
        PHEND;
        // ---- P3: q(1,1); stage A1(t+2) ----
        if (st) ST_A(t + 2, 1);
        MFMA16(4, 2, a_hi, b_hi);
        PHEND;
        // ---- P4: q(1,0) (b_lo kept from P1); stage B0(t+2); vmcnt ----
        if (st) ST_B(t + 2, 0);
        MFMA16(4, 0, a_hi, b_lo);
        if (st) {
            asm volatile("s_waitcnt vmcnt(8)" ::: "memory");
        } else if (t + 1 < nt) {
            asm volatile("s_waitcnt vmcnt(0)" ::: "memory");
        }
        __builtin_amdgcn_sched_barrier(0);
        __builtin_amdgcn_s_barrier();
        // ---- cross-tile q1 fragment reads (tile t+1) ----
        if (t + 1 < nt) {
            const int dn = ((t + 1) & 1) << 1;
            RD_A(a_lo, dn, 0); RD_B(b_lo, dn, 0);
            asm volatile("s_waitcnt lgkmcnt(0)" ::: "memory");
            __builtin_amdgcn_sched_barrier(0);
        }
    }
#undef ST_A
#undef ST_B
#undef RD_A
#undef RD_B
#undef MFMA16
#undef PHEND

    // ---- epilogue: C/D layout col=lane&15, row=(lane>>4)*4+reg ----
    const int z  = (MODE == 0) ? (n0 >> 10) : 0;
    const float* bz = (MODE == 1) ? B0 : (z == 0 ? B0 : (z == 1 ? B1 : B2));

    #pragma unroll
    for (int ni = 0; ni < 4; ++ni) {
        const int gc   = n0 + ni * 64 + wc * 16 + fr;
        const int gcol = gc & (DMODEL - 1);
        const float bv = bz[gcol];
        #pragma unroll
        for (int mi = 0; mi < 8; ++mi) {
            const int gr = i0 + mi * 32 + wr * 16 + fh * 4;
            const floatx4 v = acc[mi][ni];
            if (MODE == 0) {
                _Float16* outh = (_Float16*)out_base
                               + (size_t)z * ((size_t)16384 * DMODEL);
                const int bb = gr >> 12;
                const int sp = gr & (S_LEN - 1);
                const int hh = gcol >> 6;
                const int dh = gcol & 63;
                if (z < 2) {
                    #pragma unroll
                    for (int r = 0; r < 4; ++r)
                        outh[((((size_t)(bb * NHEADS + hh)) * S_LEN + sp + r) << 6) + dh] =
                            (_Float16)(v[r] + bv);
                } else {
                    half4_t hv;
                    hv[0] = (_Float16)(v[0] + bv); hv[1] = (_Float16)(v[1] + bv);
                    hv[2] = (_Float16)(v[2] + bv); hv[3] = (_Float16)(v[3] + bv);
                    *(half4_t*)&outh[(((size_t)(bb * NHEADS + hh)) * DHEAD + dh) * S_LEN + sp] = hv;
                }
            } else {
                float* out = (float*)out_base;
                #pragma unroll
                for (int r = 0; r < 4; ++r)
                    out[(size_t)(gr + r) * DMODEL + gcol] = v[r] + bv;
            }
        }
    }
}

// ---------------- MFMA windowed attention, wave-local exact prefix scan ---
// r13 verified kernel + XCD-aware qb swizzle (T1): blockIdx.x%8 == XCD
// (linear id = x + 64*(y+16z), 64%8==0), so map XCD k to CONSECUTIVE
// q-blocks 8k..8k+7 of each (b,h): their shared K/V band (~80 KB) is
// L2-resident, killing the ~8x cross-XCD KV re-fetch. Pure permutation
// of block work -> bit-identical output.
__global__ __launch_bounds__(256)
void attn_mfma(const _Float16* __restrict__ qh_, const _Float16* __restrict__ kh_,
               const _Float16* __restrict__ vth_, _Float16* __restrict__ o)
{
    __shared__ __align__(16) _Float16 Qs[64 * 64];
    __shared__ __align__(16) _Float16 Ks[64 * 64];
    __shared__ __align__(16) _Float16 Vt[64 * 64];
    __shared__ __align__(16) float    SP[64 * 68];
    __shared__ __align__(16) _Float16 P16[64 * 64];
    __shared__ float TqL[64];

    const int tid   = threadIdx.x;
    const int lane  = tid & 63;
    const int w     = tid >> 6;
    const int qbs   = (blockIdx.x & 7) * 8 + (blockIdx.x >> 3);  // XCD swizzle
    const int qbase = qbs * 64;
    const int head  = blockIdx.y, b = blockIdx.z;
    const size_t bh = (size_t)(b * NHEADS + head);

    const _Float16* qg = qh_  + bh * (size_t)(S_LEN * DHEAD);
    const _Float16* kg = kh_  + bh * (size_t)(S_LEN * DHEAD);
    const _Float16* vg = vth_ + bh * (size_t)(DHEAD * S_LEN);

    const int fr  = lane & 15;
    const int fh  = lane >> 4;
    const int sqt = 16 * w + (lane >> 2);
    const int sg  = lane & 3;
    const int gb  = lane & ~3;

    #pragma unroll
    for (int rep = 0; rep < 2; ++rep) {
        const int c = tid + 256 * rep;
        const int row = c >> 3, sll = c & 7;
        gload16(qg + (size_t)(qbase + row) * 64 + (size_t)((sll ^ (row & 7)) * 8),
                Qs + (size_t)c * 8);
    }

    float mq = -INFINITY;
    float tq = 0.f;

    floatx4 Oacc[4];
    #pragma unroll
    for (int ni = 0; ni < 4; ++ni) Oacc[ni] = (floatx4)0.f;

    for (int c = 0; c < 5; ++c) {
        const int jlo = qbase - WIN + c * 64;
        if (jlo < 0 || jlo >= S_LEN) continue;
        const int base_rel = jlo - qbase + WIN;

        __syncthreads();

        #pragma unroll
        for (int rep = 0; rep < 2; ++rep) {
            const int cc = tid + 256 * rep;
            const int row = cc >> 3, sll = cc & 7;
            gload16(kg + (size_t)(jlo + row) * 64 + (size_t)((sll ^ (row & 7)) * 8),
                    Ks + (size_t)cc * 8);
            gload16(vg + (size_t)row * S_LEN + jlo + (size_t)((sll ^ (row & 7)) * 8),
                    Vt + (size_t)cc * 8);
        }
        __syncthreads();

        {
            floatx4 acc[4];
            #pragma unroll
            for (int ni = 0; ni < 4; ++ni) acc[ni] = (floatx4)0.f;
            half8 a[2];
            #pragma unroll
            for (int kc = 0; kc < 2; ++kc) {
                const int row = 16 * w + fr;
                a[kc] = *(const half8*)&Qs[row * 64 + ((fh + 4 * kc) ^ (row & 7)) * 8];
            }
            #pragma unroll
            for (int ni = 0; ni < 4; ++ni)
                #pragma unroll
                for (int kc = 0; kc < 2; ++kc) {
                    const int tr = 16 * ni + fr;
                    half8 bf = *(const half8*)&Ks[tr * 64 + ((fh + 4 * kc) ^ (tr & 7)) * 8];
                    acc[ni] = __builtin_amdgcn_mfma_f32_16x16x32_f16(a[kc], bf, acc[ni], 0, 0, 0);
                }
            #pragma unroll
            for (int ni = 0; ni < 4; ++ni)
                #pragma unroll
                for (int r = 0; r < 4; ++r)
                    SP[(16 * w + 4 * fh + r) * 68 + fr + 16 * ni] = acc[ni][r] * 0.125f;
        }
        asm volatile("s_waitcnt lgkmcnt(0)" ::: "memory");
        __builtin_amdgcn_sched_barrier(0);

        {
            float sv[16], run[16];
            float m_run = -INFINITY;
            #pragma unroll
            for (int u = 0; u < 4; ++u) {
                const float4 s4 = *(const float4*)&SP[sqt * 68 + sg * 16 + 4 * u];
                const float se[4] = {s4.x, s4.y, s4.z, s4.w};
                #pragma unroll
                for (int e = 0; e < 4; ++e) {
                    const int i = 4 * u + e;
                    const int rel = base_rel + sg * 16 + i - sqt;
                    const bool valid = (rel >= 0) && (rel <= 2 * WIN);
                    const float s = valid ? se[e] : -INFINITY;
                    sv[i] = s;
                    m_run = fmaxf(m_run, s);
                    run[i] = m_run;
                }
            }
            const float cm = m_run;
            const float c0 = __shfl(cm, gb + 0);
            const float c1 = __shfl(cm, gb + 1);
            const float c2 = __shfl(cm, gb + 2);
            const float c3 = __shfl(cm, gb + 3);
            float pre = mq;
            if (sg > 0) pre = fmaxf(pre, c0);
            if (sg > 1) pre = fmaxf(pre, c1);
            if (sg > 2) pre = fmaxf(pre, c2);

            float tl = 0.f;
            _Float16 pf[16];
            #pragma unroll
            for (int i = 0; i < 16; ++i) {
                const float wm = fmaxf(pre, run[i]);
                const float p = (sv[i] != -INFINITY) ? __expf(sv[i] - wm) : 0.f;
                tl += p;
                pf[i] = (_Float16)p;
            }
            #pragma unroll
            for (int u = 0; u < 2; ++u) {
                half8 h8;
                #pragma unroll
                for (int e = 0; e < 8; ++e) h8[e] = pf[8 * u + e];
                *(half8*)&P16[sqt * 64 + ((2 * sg + u) ^ (sqt & 7)) * 8] = h8;
            }
            const float t0 = __shfl(tl, gb + 0);
            const float t1 = __shfl(tl, gb + 1);
            const float t2 = __shfl(tl, gb + 2);
            const float t3 = __shfl(tl, gb + 3);
            tq += t0 + t1 + t2 + t3;
            mq = fmaxf(mq, fmaxf(fmaxf(c0, c1), fmaxf(c2, c3)));
        }
        asm volatile("s_waitcnt lgkmcnt(0)" ::: "memory");
        __builtin_amdgcn_sched_barrier(0);

        {
            half8 pa[2];
            #pragma unroll
            for (int kc = 0; kc < 2; ++kc) {
                const int row = 16 * w + fr;
                pa[kc] = *(const half8*)&P16[row * 64 + ((fh + 4 * kc) ^ (row & 7)) * 8];
            }
            #pragma unroll
            for (int ni = 0; ni < 4; ++ni)
                #pragma unroll
                for (int kc = 0; kc < 2; ++kc) {
                    const int dr = 16 * ni + fr;
                    half8 bf = *(const half8*)&Vt[dr * 64 + ((fh + 4 * kc) ^ (dr & 7)) * 8];
                    Oacc[ni] = __builtin_amdgcn_mfma_f32_16x16x32_f16(pa[kc], bf, Oacc[ni], 0, 0, 0);
                }
        }
    }

    if (sg == 0) TqL[sqt] = tq;
    asm volatile("s_waitcnt lgkmcnt(0)" ::: "memory");
    __builtin_amdgcn_sched_barrier(0);

    #pragma unroll
    for (int ni = 0; ni < 4; ++ni)
        #pragma unroll
        for (int r = 0; r < 4; ++r) {
            const int q  = 16 * w + 4 * fh + r;
            const float inv = 1.0f / TqL[q];
            o[((size_t)(b * S_LEN + qbase + q) * NHEADS + head) * DHEAD + fr + 16 * ni] =
                (_Float16)(Oacc[ni][r] * inv);
        }
}

extern "C" void kernel_launch(void* const* d_in, const int* in_sizes, int n_in,
                              void* d_out, int out_size, void* d_ws, size_t ws_size,
                              hipStream_t stream) {
    const float* x  = (const float*)d_in[0];
    const float* wq = (const float*)d_in[1];
    const float* bq = (const float*)d_in[2];
    const float* wk = (const float*)d_in[3];
    const float* bk = (const float*)d_in[4];
    const float* wv = (const float*)d_in[5];
    const float* bv = (const float*)d_in[6];
    const float* wo = (const float*)d_in[7];
    const float* bo = (const float*)d_in[8];

    const size_t BUF = (size_t)BATCH * S_LEN * DMODEL;   // 16,777,216 elems
    _Float16* xh  = (_Float16*)d_ws;
    _Float16* qh  = xh + BUF;
    _Float16* kh  = qh + BUF;       // qh/kh/vth consecutive (z-slab offset)
    _Float16* vth = kh + BUF;
    _Float16* oh  = vth + BUF;
    _Float16* wqh = oh + BUF;       // wqh/wkh/wvh consecutive = W_all [3072,1024]
    _Float16* wkh = wqh + DMODEL * DMODEL;
    _Float16* wvh = wkh + DMODEL * DMODEL;
    _Float16* woh = wvh + DMODEL * DMODEL;

    // 1) fp32 -> f16 conversions (single launch; y=0 x, y=1..4 weights)
    cvt5_f32_f16<<<dim3(512, 5), 256, 0, stream>>>(
        (const float4*)x, (half4_t*)xh, (int)(BUF / 4),
        (const float4*)wq, (const float4*)wk, (const float4*)wv, (const float4*)wo,
        (half4_t*)wqh, (half4_t*)wkh, (half4_t*)wvh, (half4_t*)woh,
        DMODEL * DMODEL / 4);

    // 2) fused QKV projection: [16384,1024] @ [3072,1024]^T
    gemm8p<0, 12><<<64 * 12, 512, 0, stream>>>(xh, wqh, bq, bk, bv, (void*)qh);

    // 3) MFMA windowed attention -> oh f16 [B,S,H,Dh] (XCD-swizzled qb)
    dim3 gattn(S_LEN / 64, NHEADS, BATCH);
    attn_mfma<<<gattn, 256, 0, stream>>>(qh, kh, vth, oh);

    // 4) output projection -> fp32 d_out
    gemm8p<1, 4><<<64 * 4, 512, 0, stream>>>(oh, woh, bo, bo, bo, d_out);
}